// Round 8
// baseline (107.585 us; speedup 1.0000x reference)
//
#include <hip/hip_runtime.h>

typedef float v4f __attribute__((ext_vector_type(4)));

#define BB 8
#define NN 8192
#define MM 8192
#define SPLIT 32
#define MCHUNK (MM / SPLIT)  // 256 xyz2 points staged per block
#define P 8                  // xyz1 points per thread
#define TPB 64               // 1 wave per block

// ws layout (SoA xyz2 pack + partial mins):
//   [0, 1M)   : xs/ys/zs/w2[B*M] SoA
//   [1M, 9M)  : pmins[SPLIT][B*N]
#define ASZ (BB * MM)

__global__ __launch_bounds__(256) void chamfer_pack(const float* __restrict__ xyz2,
                                                    float* __restrict__ xs, float* __restrict__ ys,
                                                    float* __restrict__ zs, float* __restrict__ w2,
                                                    float* __restrict__ out) {
    int idx = blockIdx.x * 256 + threadIdx.x;  // 0 .. B*M-1
    if (idx == 0) out[0] = 0.0f;
    float x = xyz2[idx * 3 + 0];
    float y = xyz2[idx * 3 + 1];
    float z = xyz2[idx * 3 + 2];
    xs[idx] = x; ys[idx] = y; zs[idx] = z;
    w2[idx] = fmaf(x, x, fmaf(y, y, z * z));
}

__global__ __launch_bounds__(TPB, 6) void chamfer_min(const float* __restrict__ xyz1,
                                                      const float* __restrict__ xs,
                                                      const float* __restrict__ ys,
                                                      const float* __restrict__ zs,
                                                      const float* __restrict__ w2,
                                                      float* __restrict__ pmins) {
    __shared__ float sx[MCHUNK], sy[MCHUNK], sz[MCHUNK], sw[MCHUNK];

    // grid = 4096: low 7 bits = tile over B*N (128 tiles x 512 pts), high 5 = m-split
    int tile  = blockIdx.x & 127;
    int split = blockIdx.x >> 7;
    int batch = tile >> 4;   // 8 batches
    int nt    = tile & 15;   // 16 tiles of 512 points per batch
    int g = nt * TPB + threadIdx.x;  // this thread's 8-point group, 0..1023

    // ---- stage SoA chunk -> LDS (float4 per array per thread, coalesced) ----
    {
        int t = threadIdx.x;
        size_t o = (size_t)batch * MM + (size_t)split * MCHUNK + 4 * t;
        *(float4*)&sx[4 * t] = *(const float4*)(xs + o);
        *(float4*)&sy[4 * t] = *(const float4*)(ys + o);
        *(float4*)&sz[4 * t] = *(const float4*)(zs + o);
        *(float4*)&sw[4 * t] = *(const float4*)(w2 + o);
    }

    // ---- load this thread's 8 xyz1 points (24 floats = 6 float4) ----
    const float4* q = (const float4*)(xyz1 + ((size_t)batch * NN + (size_t)g * P) * 3);
    float f[24];
    float4* f4 = (float4*)f;
#pragma unroll
    for (int t = 0; t < 6; ++t) f4[t] = q[t];

    float bx[P], by[P], bz[P], x2[P], m[P];
#pragma unroll
    for (int p = 0; p < P; ++p) {
        float ax = f[3 * p + 0], ay = f[3 * p + 1], az = f[3 * p + 2];
        x2[p] = fmaf(ax, ax, fmaf(ay, ay, az * az));
        bx[p] = -2.0f * ax;
        by[p] = -2.0f * ay;
        bz[p] = -2.0f * az;
        m[p] = 1e30f;
    }

    __syncthreads();

    // ---- main loop: 4 j's/iter, register double-buffered b128 SoA reads ----
    v4f wx = *(const v4f*)&sx[0];
    v4f wy = *(const v4f*)&sy[0];
    v4f wz = *(const v4f*)&sz[0];
    v4f ww = *(const v4f*)&sw[0];
#pragma unroll 1
    for (int j = 0; j < MCHUNK; j += 4) {
        v4f cwx = wx, cwy = wy, cwz = wz, cww = ww;
        int jn = (j + 4) & (MCHUNK - 1);  // prefetch next quad (wraps harmlessly on last)
        wx = *(const v4f*)&sx[jn];
        wy = *(const v4f*)&sy[jn];
        wz = *(const v4f*)&sz[jn];
        ww = *(const v4f*)&sw[jn];
#pragma unroll
        for (int p = 0; p < P; ++p) {
            float d0 = fmaf(bx[p], cwx.x, fmaf(by[p], cwy.x, fmaf(bz[p], cwz.x, cww.x)));
            float d1 = fmaf(bx[p], cwx.y, fmaf(by[p], cwy.y, fmaf(bz[p], cwz.y, cww.y)));
            float d2 = fmaf(bx[p], cwx.z, fmaf(by[p], cwy.z, fmaf(bz[p], cwz.z, cww.z)));
            float d3 = fmaf(bx[p], cwx.w, fmaf(by[p], cwy.w, fmaf(bz[p], cwz.w, cww.w)));
            // tree -> v_min_f32 x2 + v_min3_f32
            m[p] = fminf(fminf(fminf(d0, d1), fminf(d2, d3)), m[p]);
        }
    }

    // ---- epilogue: add x2, store 8 floats as 2 float4 ----
    float r[P];
#pragma unroll
    for (int p = 0; p < P; ++p) r[p] = x2[p] + m[p];
    size_t base = (size_t)split * (BB * NN) + (size_t)batch * NN + (size_t)g * P;
    float4* dst = (float4*)(pmins + base);
    dst[0] = ((float4*)r)[0];
    dst[1] = ((float4*)r)[1];
}

__global__ __launch_bounds__(256) void chamfer_reduce(const float* __restrict__ pmins,
                                                      float* __restrict__ out) {
    int i = blockIdx.x * 256 + threadIdx.x;  // grid 256 blocks, 0..65535
    float m = pmins[i];
#pragma unroll
    for (int sp = 1; sp < SPLIT; ++sp)
        m = fminf(m, pmins[(size_t)sp * (BB * NN) + i]);
    float s = m;
#pragma unroll
    for (int off = 32; off > 0; off >>= 1) s += __shfl_down(s, off);
    __shared__ float ls[4];
    int lane = threadIdx.x & 63, wv = threadIdx.x >> 6;
    if (lane == 0) ls[wv] = s;
    __syncthreads();
    if (threadIdx.x == 0) {
        float t = (ls[0] + ls[1]) + (ls[2] + ls[3]);
        atomicAdd(out, t * (1.0f / (float)(BB * NN)));
    }
}

extern "C" void kernel_launch(void* const* d_in, const int* in_sizes, int n_in,
                              void* d_out, int out_size, void* d_ws, size_t ws_size,
                              hipStream_t stream) {
    const float* xyz1 = (const float*)d_in[0];
    const float* xyz2 = (const float*)d_in[1];
    float* out = (float*)d_out;
    float* xs = (float*)d_ws;
    float* ys = xs + ASZ;
    float* zs = ys + ASZ;
    float* w2 = zs + ASZ;
    float* pmins = w2 + ASZ;

    chamfer_pack<<<(BB * MM) / 256, 256, 0, stream>>>(xyz2, xs, ys, zs, w2, out);
    chamfer_min<<<(BB * NN / (P * TPB)) * SPLIT, TPB, 0, stream>>>(xyz1, xs, ys, zs, w2, pmins);
    chamfer_reduce<<<(BB * NN) / 256, 256, 0, stream>>>(pmins, out);
}

// Round 9
// 87.337 us; speedup vs baseline: 1.2318x; 1.2318x over previous
//
#include <hip/hip_runtime.h>

typedef _Float16 v8h __attribute__((ext_vector_type(8)));
typedef float v16f __attribute__((ext_vector_type(16)));

#define BB 8
#define NN 8192   // xyz1 points per batch (i dim, output)
#define MM 8192   // xyz2 points per batch (j dim, reduced)
#define SPLITM 8            // j-chunks per batch
#define JT_PER_CHUNK 32     // j-tiles (32 pts) per chunk: 8*32*32 = 8192
#define NI 2                // i-tiles per wave
#define TPB 256             // 4 waves

// ws layout:
//   [0, 2M)   : afrag[b][jt][lane] v8h   (xyz2 side, MFMA A layout)   8*256*64*16B
//   [2M, 4M)  : bfrag[b][it][lane] v8h   (xyz1 side, MFMA B layout)
//   [4M, 6M)  : pmins[SPLITM][B*N] float
#define AFRAG_OFF 0
#define BFRAG_OFF (8 * 256 * 64 * 16)
#define PMINS_OFF (2 * BFRAG_OFF)

// Homogeneous K=16 encoding (k = (lane>>5)*8 + reg):
//  k=0..2 : A = yhat_c          B = -2*xhat_c
//  k=3,4  : A = (y2)_hi,(y2)_lo B = 1, 1
//  k=5,6  : A = 1, 1            B = (x2)_hi,(x2)_lo
//  k>=7   : 0
// => D[j][i] = |xhat_i - yhat_j|^2 exactly (fp32 accum), no cancellation loss.

__global__ __launch_bounds__(256) void pack_a(const float* __restrict__ xyz2,
                                              v8h* __restrict__ afrag,
                                              float* __restrict__ out) {
    int gid = blockIdx.x * 256 + threadIdx.x;  // b*16384 + jt*64 + lane
    if (gid == 0) out[0] = 0.0f;
    int lane = gid & 63;
    int jt = (gid >> 6) & 255;
    int b = gid >> 14;
    int j = jt * 32 + (lane & 31);
    int khalf = lane >> 5;
    const float* p = xyz2 + ((size_t)b * MM + j) * 3;
    _Float16 h0 = (_Float16)p[0], h1 = (_Float16)p[1], h2 = (_Float16)p[2];
    float y0 = (float)h0, y1 = (float)h1, y2v = (float)h2;
    float s = fmaf(y0, y0, fmaf(y1, y1, y2v * y2v));
    _Float16 shi = (_Float16)s;
    _Float16 slo = (_Float16)(s - (float)shi);
    v8h v = {0, 0, 0, 0, 0, 0, 0, 0};
    if (khalf == 0) {
        v[0] = h0; v[1] = h1; v[2] = h2;
        v[3] = shi; v[4] = slo;
        v[5] = (_Float16)1.0f; v[6] = (_Float16)1.0f;
    }
    afrag[gid] = v;
}

__global__ __launch_bounds__(256) void pack_b(const float* __restrict__ xyz1,
                                              v8h* __restrict__ bfrag) {
    int gid = blockIdx.x * 256 + threadIdx.x;  // b*16384 + it*64 + lane
    int lane = gid & 63;
    int it = (gid >> 6) & 255;
    int b = gid >> 14;
    int i = it * 32 + (lane & 31);
    int khalf = lane >> 5;
    const float* p = xyz1 + ((size_t)b * NN + i) * 3;
    _Float16 h0 = (_Float16)p[0], h1 = (_Float16)p[1], h2 = (_Float16)p[2];
    float x0 = (float)h0, x1 = (float)h1, x2v = (float)h2;
    float s = fmaf(x0, x0, fmaf(x1, x1, x2v * x2v));
    _Float16 shi = (_Float16)s;
    _Float16 slo = (_Float16)(s - (float)shi);
    v8h v = {0, 0, 0, 0, 0, 0, 0, 0};
    if (khalf == 0) {
        v[0] = (_Float16)(-2.0f * x0);  // exact: f16 * 2, negate
        v[1] = (_Float16)(-2.0f * x1);
        v[2] = (_Float16)(-2.0f * x2v);
        v[3] = (_Float16)1.0f; v[4] = (_Float16)1.0f;
        v[5] = shi; v[6] = slo;
    }
    bfrag[gid] = v;
}

__global__ __launch_bounds__(TPB, 4) void chamfer_min_mfma(const v8h* __restrict__ afrag,
                                                           const v8h* __restrict__ bfrag,
                                                           float* __restrict__ pmins) {
    __shared__ v8h aLds[JT_PER_CHUNK * 64];  // 32 KB

    // grid = 2048: bid = b*256 + jchunk*32 + ig4
    int ig4    = blockIdx.x & 31;
    int jchunk = (blockIdx.x >> 5) & 7;
    int b      = blockIdx.x >> 8;
    int wid  = threadIdx.x >> 6;
    int lane = threadIdx.x & 63;

    // ---- stage this chunk's A-frag stream -> LDS (coalesced dwordx4) ----
    {
        const uint4* src = (const uint4*)(afrag + ((size_t)b * 256 + jchunk * JT_PER_CHUNK) * 64);
        uint4* dst = (uint4*)aLds;
#pragma unroll
        for (int r = 0; r < JT_PER_CHUNK * 64 / TPB; ++r)
            dst[r * TPB + threadIdx.x] = src[r * TPB + threadIdx.x];
    }

    // ---- this wave's two i-tiles: B-frags live in registers ----
    int it0 = (ig4 * 4 + wid) * NI;
    v8h b0 = bfrag[((size_t)b * 256 + it0 + 0) * 64 + lane];
    v8h b1 = bfrag[((size_t)b * 256 + it0 + 1) * 64 + lane];

    __syncthreads();

    const v16f zc = {0, 0, 0, 0, 0, 0, 0, 0, 0, 0, 0, 0, 0, 0, 0, 0};
    float m0 = 1e30f, m1 = 1e30f;

#pragma unroll 2
    for (int jt = 0; jt < JT_PER_CHUNK; ++jt) {
        v8h a = aLds[jt * 64 + lane];
        v16f c0 = __builtin_amdgcn_mfma_f32_32x32x16_f16(a, b0, zc, 0, 0, 0);
        v16f c1 = __builtin_amdgcn_mfma_f32_32x32x16_f16(a, b1, zc, 0, 0, 0);
#pragma unroll
        for (int r = 0; r < 16; r += 4) {
            m0 = fminf(m0, fminf(fminf(c0[r], c0[r + 1]), fminf(c0[r + 2], c0[r + 3])));
            m1 = fminf(m1, fminf(fminf(c1[r], c1[r + 1]), fminf(c1[r + 2], c1[r + 3])));
        }
    }

    // rows split across lane halves: combine
    m0 = fminf(m0, __shfl_xor(m0, 32));
    m1 = fminf(m1, __shfl_xor(m1, 32));

    // lanes 0..31 write tile it0, lanes 32..63 write tile it0+1
    int half = lane >> 5;
    int i = (it0 + half) * 32 + (lane & 31);
    float mv = half ? m1 : m0;
    pmins[(size_t)jchunk * (BB * NN) + (size_t)b * NN + i] = mv;
}

__global__ __launch_bounds__(256) void chamfer_reduce(const float* __restrict__ pmins,
                                                      float* __restrict__ out) {
    int i = blockIdx.x * 256 + threadIdx.x;  // grid 256 blocks, 0..65535
    float m = pmins[i];
#pragma unroll
    for (int sp = 1; sp < SPLITM; ++sp)
        m = fminf(m, pmins[(size_t)sp * (BB * NN) + i]);
    float s = m;
#pragma unroll
    for (int off = 32; off > 0; off >>= 1) s += __shfl_down(s, off);
    __shared__ float ls[4];
    int lane = threadIdx.x & 63, wv = threadIdx.x >> 6;
    if (lane == 0) ls[wv] = s;
    __syncthreads();
    if (threadIdx.x == 0) {
        float t = (ls[0] + ls[1]) + (ls[2] + ls[3]);
        atomicAdd(out, t * (1.0f / (float)(BB * NN)));
    }
}

extern "C" void kernel_launch(void* const* d_in, const int* in_sizes, int n_in,
                              void* d_out, int out_size, void* d_ws, size_t ws_size,
                              hipStream_t stream) {
    const float* xyz1 = (const float*)d_in[0];
    const float* xyz2 = (const float*)d_in[1];
    float* out = (float*)d_out;
    v8h* afrag = (v8h*)((char*)d_ws + AFRAG_OFF);
    v8h* bfrag = (v8h*)((char*)d_ws + BFRAG_OFF);
    float* pmins = (float*)((char*)d_ws + PMINS_OFF);

    pack_a<<<(BB * 256 * 64) / 256, 256, 0, stream>>>(xyz2, afrag, out);
    pack_b<<<(BB * 256 * 64) / 256, 256, 0, stream>>>(xyz1, bfrag);
    chamfer_min_mfma<<<BB * SPLITM * 32, TPB, 0, stream>>>(afrag, bfrag, pmins);
    chamfer_reduce<<<(BB * NN) / 256, 256, 0, stream>>>(pmins, out);
}